// Round 5
// baseline (475.440 us; speedup 1.0000x reference)
//
#include <hip/hip_runtime.h>

// LSTM: B=4096, T=2048, I=4, H=3, gates i,f,g,o (W rows r = g*3 + u)
// R5: 16 lanes per sequence (quad q = unit, q==3 dup; lane-in-quad s = gate).
//     Transcendental-free activations: tanh via exact Pade/continued-fraction
//     rational (1 rcp per hop instead of exp2->rcp), sigma(a)=0.5+0.5*T(a/2).
//     o-gate folded into dot weights off-cycle (ror tc, not o*tc).

#define BB 4096
#define TT 2048

template<int CTRL>
__device__ __forceinline__ int dpp_i(int v) {
    return __builtin_amdgcn_update_dpp(0, v, CTRL, 0xF, 0xF, true);
}
template<int CTRL>
__device__ __forceinline__ float dpp_f(float v) {
    return __int_as_float(dpp_i<CTRL>(__float_as_int(v)));
}
#define ROR4  0x124
#define ROR8  0x128
#define ROR12 0x12C

// tanh(z) for |z|<=4.25 via CF-5 Pade: z*N(w)/D(w), w=z^2.
// max abs err <= 2e-4 on range; clamp residual <= 7.4e-4 for |z|>4.25.
__device__ __forceinline__ float tanh_pade(float zc) {
    const float w = zc * zc;
    const float N = fmaf(fmaf(21.f, w, 1260.f), w, 10395.f);
    const float D = fmaf(fmaf((w + 210.f), w, 4725.f), w, 10395.f);
    return zc * (N * __builtin_amdgcn_rcpf(D));
}

__global__ __launch_bounds__(64, 1) void lstm_seq(
    const float* __restrict__ x, const float* __restrict__ Wih,
    const float* __restrict__ Whh, const float* __restrict__ bih,
    const float* __restrict__ bhh, const int* __restrict__ len,
    float* __restrict__ out)
{
    const int lane  = threadIdx.x & 63;
    const int s     = lane & 3;          // gate: 0=i,1=f,2=g,3=o
    const int q     = (lane >> 2) & 3;   // quad = unit (3 = dup of unit 2)
    const int row16 = lane >> 4;         // sequence within wave (4 per wave)
    const int b     = blockIdx.x * 4 + row16;
    const int u     = (q < 3) ? q : 2;
    const int wrow  = s * 3 + u;

    // sigma gates (s!=2): sig(a) = 0.5 + 0.5*T(a/2)  -> prescale 0.5, affine (0.5,0.5)
    // g gate     (s==2): tanh(a) = T(a)              -> prescale 1.0, affine (0,1)
    const float wscale = (s == 2) ? 1.f : 0.5f;
    const float Aa = (s == 2) ? 0.f : 0.5f;
    const float Bb = (s == 2) ? 1.f : 0.5f;

    const float xw0 = Wih[wrow * 4 + 0] * wscale;
    const float xw1 = Wih[wrow * 4 + 1] * wscale;
    const float xw2 = Wih[wrow * 4 + 2] * wscale;
    const float xw3 = Wih[wrow * 4 + 3] * wscale;
    const float bias = (bih[wrow] + bhh[wrow]) * wscale;

    // Runtime probe: which quad's value arrives in each ror slot?
    const int p1 = (dpp_i<ROR4 >(lane) >> 2) & 3;
    const int p2 = (dpp_i<ROR8 >(lane) >> 2) & 3;
    const int p3 = (dpp_i<ROR12>(lane) >> 2) & 3;
    const int srcq[4] = {q, p1, p2, p3};
    float wh[4];
    #pragma unroll
    for (int j = 0; j < 4; ++j)
        wh[j] = (srcq[j] == 3) ? 0.f : Whh[wrow * 3 + srcq[j]] * wscale;

    const int mylen = len[b];
    int wmax = mylen;
    #pragma unroll
    for (int off = 1; off < 64; off <<= 1)
        wmax = max(wmax, __shfl_xor(wmax, off));
    const int Tloop = (wmax + 7) & ~7;

    // Loop state: c, rotated tanh(c) per slot, o-folded dot weights per slot.
    float c = 0.f;
    float tcr0 = 0.f, tcr1 = 0.f, tcr2 = 0.f, tcr3 = 0.f;
    float whg0 = 0.f, whg1 = 0.f, whg2 = 0.f, whg3 = 0.f;
    float go = 0.f;  // own-quad o gate (for the h store)

    const float4* __restrict__ xrow = ((const float4*)x) + (size_t)b * TT;
    float* __restrict__ orow = out + (size_t)b * (TT * 3);
    const bool writer = (s == 0) && (q < 3);

    float4 buf[8];
    float xacc[8];
    #pragma unroll
    for (int uu = 0; uu < 8; ++uu) buf[uu] = xrow[uu];

    for (int tb = 0; tb < Tloop; tb += 8) {
        #pragma unroll
        for (int uu = 0; uu < 8; ++uu) {
            const float4 xv = buf[uu];
            xacc[uu] = fmaf(xw3, xv.w, fmaf(xw2, xv.z,
                       fmaf(xw1, xv.y, fmaf(xw0, xv.x, bias))));
        }
        #pragma unroll
        for (int uu = 0; uu < 8; ++uu) {
            const int tn = tb + 8 + uu;
            buf[uu] = xrow[tn < TT ? tn : 0];
        }
        #pragma unroll
        for (int uu = 0; uu < 8; ++uu) {
            const int t = tb + uu;
            // dot over o-folded weights and rotated tanh(c): depth-3 from tcr
            const float d0 = fmaf(whg1, tcr1, fmaf(whg0, tcr0, xacc[uu]));
            const float d1 = fmaf(whg3, tcr3, whg2 * tcr2);
            const float a  = d0 + d1;                 // prescaled gate input
            const float z  = __builtin_amdgcn_fmed3f(a, -4.25f, 4.25f);
            const float act = fmaf(Bb, tanh_pade(z), Aa);
            const float gi = dpp_f<0x00>(act);        // i (sigmoid)
            const float gf = dpp_f<0x55>(act);        // f (sigmoid)
            const float gg = dpp_f<0xAA>(act);        // g (tanh)
            go             = dpp_f<0xFF>(act);        // o (sigmoid)
            c = fmaf(gf, c, gi * gg);
            // off-cycle: rotate o and fold into next dot's weights
            const float go1 = dpp_f<ROR4 >(go);
            const float go2 = dpp_f<ROR8 >(go);
            const float go3 = dpp_f<ROR12>(go);
            whg0 = wh[0] * go;  whg1 = wh[1] * go1;
            whg2 = wh[2] * go2; whg3 = wh[3] * go3;
            // tanh hop on the cycle
            const float zc = __builtin_amdgcn_fmed3f(c, -4.25f, 4.25f);
            const float tc = tanh_pade(zc);
            tcr0 = tc;
            tcr1 = dpp_f<ROR4 >(tc);
            tcr2 = dpp_f<ROR8 >(tc);
            tcr3 = dpp_f<ROR12>(tc);
            if (writer) orow[t * 3 + q] = (t < mylen) ? (go * tc) : 0.f;
        }
    }

    // Zero the remaining tail t in [Tloop, TT) for this wave's 4 rows.
    const int start4 = Tloop * 3 / 4;          // multiple of 6, 16B-aligned
    #pragma unroll
    for (int rr = 0; rr < 4; ++rr) {
        float4* __restrict__ o4 = (float4*)(out + ((size_t)(blockIdx.x * 4 + rr)) * (TT * 3));
        for (int idx = start4 + lane; idx < TT * 3 / 4; idx += 64)
            o4[idx] = make_float4(0.f, 0.f, 0.f, 0.f);
    }
}

extern "C" void kernel_launch(void* const* d_in, const int* in_sizes, int n_in,
                              void* d_out, int out_size, void* d_ws, size_t ws_size,
                              hipStream_t stream) {
    const float* x    = (const float*)d_in[0];
    const float* Wih  = (const float*)d_in[1];
    const float* Whh  = (const float*)d_in[2];
    const float* bih  = (const float*)d_in[3];
    const float* bhh  = (const float*)d_in[4];
    const int*   lenp = (const int*)d_in[5];
    float* out = (float*)d_out;

    lstm_seq<<<BB / 4, 64, 0, stream>>>(x, Wih, Whh, bih, bhh, lenp, out);
}